// Round 3
// baseline (663.203 us; speedup 1.0000x reference)
//
#include <hip/hip_runtime.h>

// AdaptiveStdPooling2d: x [B=16, C=128, H=512, W=128] fp32
// H_OUT=8, W_OUT=16  ->  kh = 64 (variance axis), kw = 8 (std-sum axis)
// out[b,c,ho,wo] = sum_{j<8} sqrt( var_{r<64}( x[b,c,ho*64+r, wo*8+j] ) + 1e-14 )
//
// Slab (b,c,ho) = 64 rows x 128 cols = contiguous 32 KiB of x.
// One wave per slab-pass; lane layout: cg = lane&31 owns cols 4cg..4cg+3,
// rh = lane>>5 owns rows {2k+rh} -> each wave-load = ONE contiguous 1-KiB
// segment; unroll-4 group = 4 KiB contiguous.
//
// R3: test the untested {cached loads x good-occupancy} cell.
//   Evidence so far: R0 (nt, full unroll) == R1 (cached, full unroll) ==
//   R2 (nt, unroll4, bounds(256,4)) -- all ~180 us kernel (~2.9 TB/s read,
//   from profiled inter-fill spacing 511us - fill 330us). Roofline ~85-105us.
//   R1's cached test was confounded by the full-unroll config; the 4.89 TB/s
//   read-dominated reference (RMSNorm) uses plain cached loads + modest
//   unroll + high occupancy = exactly this config.
//   Also: canonical 2048-block grid, 2 slabs/wave (two independent load
//   streams the compiler may interleave -> up to 8 loads in flight/wave).

#define KH 64
#define WIDTH 128
#define W_OUT 16
#define SLABS 16384        // B*C*H_OUT = 16*128*8
#define BLOCKS 2048        // 4 waves/block -> 8192 waves -> 2 slabs/wave
#define WAVES_TOTAL 8192

typedef float f32x4 __attribute__((ext_vector_type(4)));

__global__ __launch_bounds__(256, 4) void adaptive_std_pool_kernel(
    const float* __restrict__ x, float* __restrict__ out) {
    const int wave = threadIdx.x >> 6;       // 0..3
    const int lane = threadIdx.x & 63;
    const int cg = lane & 31;                // column group: cols 4cg..4cg+3
    const int rh = lane >> 5;                // row parity: rows 2k+rh

    const int wid = blockIdx.x * 4 + wave;   // [0, 8192)

#pragma unroll
    for (int t = 0; t < 2; ++t) {
        const int slab = wid + t * WAVES_TOTAL;   // [0, 16384)
        const f32x4* p = (const f32x4*)(x + (size_t)slab * KH * WIDTH)
                         + (size_t)rh * (WIDTH / 4) + cg;

        f32x4 s  = {0.f, 0.f, 0.f, 0.f};
        f32x4 ss = {0.f, 0.f, 0.f, 0.f};
#pragma unroll 4
        for (int k = 0; k < 32; ++k) {
            // rows {2k, 2k+1}: stride 2 rows = 64 float4 = 1 KiB
            f32x4 v = p[(size_t)k * (2 * WIDTH / 4)];
            s += v;
            ss += v * v;   // -ffp-contract fuses into v_fmac
        }

        // Combine the two row-parity halves (lane ^ 32, within the wave).
        s.x  += __shfl_xor(s.x, 32);  s.y  += __shfl_xor(s.y, 32);
        s.z  += __shfl_xor(s.z, 32);  s.w  += __shfl_xor(s.w, 32);
        ss.x += __shfl_xor(ss.x, 32); ss.y += __shfl_xor(ss.y, 32);
        ss.z += __shfl_xor(ss.z, 32); ss.w += __shfl_xor(ss.w, 32);

        const float inv = 1.0f / (float)KH;
        float partial = 0.f;
        {
            float m = s.x * inv;
            partial += sqrtf(fmaxf(ss.x * inv - m * m, 0.f) + 1e-14f);
        }
        {
            float m = s.y * inv;
            partial += sqrtf(fmaxf(ss.y * inv - m * m, 0.f) + 1e-14f);
        }
        {
            float m = s.z * inv;
            partial += sqrtf(fmaxf(ss.z * inv - m * m, 0.f) + 1e-14f);
        }
        {
            float m = s.w * inv;
            partial += sqrtf(fmaxf(ss.w * inv - m * m, 0.f) + 1e-14f);
        }

        // kw=8 bin = columns {8m..8m+7} = lanes {2m, 2m+1} (aligned pair).
        partial += __shfl_xor(partial, 1);

        if (rh == 0 && (lane & 1) == 0) {
            out[slab * W_OUT + (cg >> 1)] = partial;
        }
    }
}

extern "C" void kernel_launch(void* const* d_in, const int* in_sizes, int n_in,
                              void* d_out, int out_size, void* d_ws, size_t ws_size,
                              hipStream_t stream) {
    const float* x = (const float*)d_in[0];
    float* out = (float*)d_out;
    adaptive_std_pool_kernel<<<BLOCKS, 256, 0, stream>>>(x, out);
}